// Round 1
// baseline (16861.650 us; speedup 1.0000x reference)
//
#include <hip/hip_runtime.h>

#define N_NODES 8192
#define E_EDGES 262144
#define ET (E_EDGES + N_NODES)   /* 270336 edges incl. self-loops */

/* d_out layout (float32):
   [0,1536) logits; a1 @1536; a2 @271872; a3 @542208; srcdst @812544 (2 x ET) */
#define O_A1 1536
#define O_A2 (O_A1 + ET)
#define O_A3 (O_A2 + ET)
#define O_SD (O_A3 + ET)

static __device__ __forceinline__ float tanh_fast(float x) {
    x = fminf(fmaxf(x, -15.f), 15.f);
    float e = __expf(2.f * x);
    return (e - 1.f) / (e + 1.f);
}

/* ---------- edge prep ---------- */
__global__ __launch_bounds__(256) void k_edges(const int* __restrict__ ei,
                                               int* __restrict__ src_i, int* __restrict__ dst_i,
                                               float* __restrict__ out_sd, int* __restrict__ counts) {
    int i = blockIdx.x * 256 + threadIdx.x;
    if (i >= ET) return;
    int s, d;
    if (i < E_EDGES) { s = ei[i]; d = ei[E_EDGES + i]; }
    else { s = d = i - E_EDGES; }
    src_i[i] = s; dst_i[i] = d;
    out_sd[i] = (float)s;
    out_sd[ET + i] = (float)d;
    atomicAdd(&counts[d], 1);
}

__global__ __launch_bounds__(1024) void k_scan(const int* __restrict__ counts,
                                               int* __restrict__ rowptr, int* __restrict__ cursor) {
    __shared__ int part[1024];
    const int tid = threadIdx.x;
    const int base = tid * 8;
    int loc[8]; int run = 0;
#pragma unroll
    for (int i = 0; i < 8; ++i) { loc[i] = run; run += counts[base + i]; }
    part[tid] = run;
    __syncthreads();
    for (int off = 1; off < 1024; off <<= 1) {
        int v = (tid >= off) ? part[tid - off] : 0;
        __syncthreads();
        part[tid] += v;
        __syncthreads();
    }
    int pre = tid ? part[tid - 1] : 0;
#pragma unroll
    for (int i = 0; i < 8; ++i) {
        int v = pre + loc[i];
        rowptr[base + i] = v;
        cursor[base + i] = v;
    }
    if (tid == 1023) rowptr[N_NODES] = part[1023];
}

__global__ __launch_bounds__(256) void k_scatter(const int* __restrict__ dst_i,
                                                 int* __restrict__ cursor, int* __restrict__ esort) {
    int i = blockIdx.x * 256 + threadIdx.x;
    if (i >= ET) return;
    int pos = atomicAdd(&cursor[dst_i[i]], 1);
    esort[pos] = i;
}

/* ---------- GEMM: C[M,N] = A[M,K] * B[K,N]  (B row-major k-major) ---------- */
__global__ __launch_bounds__(256) void gemm_nn(const float* __restrict__ A, const float* __restrict__ B,
                                               float* __restrict__ C, int M, int N, int K) {
    __shared__ __align__(16) float As[16][68];
    __shared__ __align__(16) float Bs[16][68];
    const int tid = threadIdx.x;
    const int tx = tid & 15, ty = tid >> 4;
    const int m0 = blockIdx.x * 64, n0 = blockIdx.y * 64;
    float acc[4][4] = {};
    for (int k0 = 0; k0 < K; k0 += 16) {
        const int ar = tid >> 4, ac = tid & 15;
#pragma unroll
        for (int i = 0; i < 4; ++i)
            As[ac][ar + i * 16] = A[(size_t)(m0 + ar + i * 16) * K + k0 + ac];
        const int br = tid >> 6, bc = tid & 63;
#pragma unroll
        for (int i = 0; i < 4; ++i)
            Bs[br + i * 4][bc] = B[(size_t)(k0 + br + i * 4) * N + n0 + bc];
        __syncthreads();
#pragma unroll
        for (int kk = 0; kk < 16; ++kk) {
            float4 a4 = *(const float4*)&As[kk][ty * 4];
            float4 b4 = *(const float4*)&Bs[kk][tx * 4];
            float av[4] = {a4.x, a4.y, a4.z, a4.w};
            float bv[4] = {b4.x, b4.y, b4.z, b4.w};
#pragma unroll
            for (int i = 0; i < 4; ++i)
#pragma unroll
                for (int j = 0; j < 4; ++j) acc[i][j] = fmaf(av[i], bv[j], acc[i][j]);
        }
        __syncthreads();
    }
#pragma unroll
    for (int i = 0; i < 4; ++i)
#pragma unroll
        for (int j = 0; j < 4; ++j)
            C[(size_t)(m0 + ty * 4 + i) * N + n0 + tx * 4 + j] = acc[i][j];
}

/* ---------- GEMM: C[M,N] = A[M,K] * B[N,K]^T, fused epilogue ---------- */
__global__ __launch_bounds__(256) void gemm_tn(const float* __restrict__ A, const float* __restrict__ B,
                                               float* __restrict__ C, int M, int N, int K,
                                               const float* __restrict__ b1, const float* __restrict__ b2,
                                               int do_relu, const float* __restrict__ bng,
                                               const float* __restrict__ bnb) {
    __shared__ __align__(16) float As[16][68];
    __shared__ __align__(16) float Bs[16][68];
    const int tid = threadIdx.x;
    const int tx = tid & 15, ty = tid >> 4;
    const int m0 = blockIdx.x * 64, n0 = blockIdx.y * 64;
    float acc[4][4] = {};
    for (int k0 = 0; k0 < K; k0 += 16) {
        const int ar = tid >> 4, ac = tid & 15;
#pragma unroll
        for (int i = 0; i < 4; ++i)
            As[ac][ar + i * 16] = A[(size_t)(m0 + ar + i * 16) * K + k0 + ac];
#pragma unroll
        for (int i = 0; i < 4; ++i) {
            int n = n0 + (tid >> 4) + i * 16;
            Bs[tid & 15][(tid >> 4) + i * 16] = (n < N) ? B[(size_t)n * K + k0 + (tid & 15)] : 0.f;
        }
        __syncthreads();
#pragma unroll
        for (int kk = 0; kk < 16; ++kk) {
            float4 a4 = *(const float4*)&As[kk][ty * 4];
            float4 b4 = *(const float4*)&Bs[kk][tx * 4];
            float av[4] = {a4.x, a4.y, a4.z, a4.w};
            float bv[4] = {b4.x, b4.y, b4.z, b4.w};
#pragma unroll
            for (int i = 0; i < 4; ++i)
#pragma unroll
                for (int j = 0; j < 4; ++j) acc[i][j] = fmaf(av[i], bv[j], acc[i][j]);
        }
        __syncthreads();
    }
#pragma unroll
    for (int i = 0; i < 4; ++i)
#pragma unroll
        for (int j = 0; j < 4; ++j) {
            int n = n0 + tx * 4 + j;
            if (n >= N) continue;
            float v = acc[i][j];
            if (b1) v += b1[n];
            if (b2) v += b2[n];
            if (do_relu) v = fmaxf(v, 0.f);
            if (bng) v = v * (bng[n] * rsqrtf(1.f + 1e-5f)) + bnb[n];
            C[(size_t)(m0 + ty * 4 + i) * N + n] = v;
        }
}

/* ---------- per-node attention scores ---------- */
__global__ __launch_bounds__(256) void attn_scores(const float* __restrict__ h,
                                                   const float* __restrict__ a_s, const float* __restrict__ a_d,
                                                   float* __restrict__ ssrc, float* __restrict__ sdst, int F) {
    const int wave = threadIdx.x >> 6, lane = threadIdx.x & 63;
    const int n = blockIdx.x * 4 + wave;
    const float* hr = h + (size_t)n * F;
    float va = 0.f, vd = 0.f;
    for (int f = lane; f < F; f += 64) { float hv = hr[f]; va += hv * a_s[f]; vd += hv * a_d[f]; }
    for (int o = 32; o; o >>= 1) { va += __shfl_down(va, o); vd += __shfl_down(vd, o); }
    if (lane == 0) { ssrc[n] = va; sdst[n] = vd; }
}

/* ---------- softmax + aggregate per dst node ---------- */
__global__ __launch_bounds__(256) void gat_agg(const float* __restrict__ h,
                                               const float* __restrict__ ssrc, const float* __restrict__ sdst,
                                               const int* __restrict__ rowptr, const int* __restrict__ esort,
                                               const int* __restrict__ src_i, const float* __restrict__ bias,
                                               float* __restrict__ outh, float* __restrict__ alpha_out, int F) {
    const int n = blockIdx.x, tid = threadIdx.x;
    const int r0 = rowptr[n], r1 = rowptr[n + 1];
    const int deg = r1 - r0;
    const float sd = sdst[n];
    __shared__ float redA[4], redB[4];
    float m = -1e30f;
    for (int j = tid; j < deg; j += 256) {
        int eid = esort[r0 + j];
        float e = ssrc[src_i[eid]] + sd;
        e = (e >= 0.f) ? e : 0.2f * e;
        m = fmaxf(m, e);
    }
    for (int o = 32; o; o >>= 1) m = fmaxf(m, __shfl_down(m, o));
    if ((tid & 63) == 0) redA[tid >> 6] = m;
    __syncthreads();
    m = fmaxf(fmaxf(redA[0], redA[1]), fmaxf(redA[2], redA[3]));
    float s = 0.f;
    for (int j = tid; j < deg; j += 256) {
        int eid = esort[r0 + j];
        float e = ssrc[src_i[eid]] + sd;
        e = (e >= 0.f) ? e : 0.2f * e;
        s += __expf(e - m);
    }
    for (int o = 32; o; o >>= 1) s += __shfl_down(s, o);
    if ((tid & 63) == 0) redB[tid >> 6] = s;
    __syncthreads();
    s = redB[0] + redB[1] + redB[2] + redB[3];
    const float inv = 1.f / (s + 1e-16f);
    __shared__ float la[256];
    __shared__ int ls[256];
    float acc = 0.f;
    for (int base = 0; base < deg; base += 256) {
        __syncthreads();
        int j = base + tid;
        if (j < deg) {
            int eid = esort[r0 + j];
            int sidx = src_i[eid];
            float e = ssrc[sidx] + sd;
            e = (e >= 0.f) ? e : 0.2f * e;
            float al = __expf(e - m) * inv;
            la[tid] = al; ls[tid] = sidx;
            alpha_out[eid] = al;
        }
        __syncthreads();
        int cnt = min(256, deg - base);
        if (tid < F) {
            for (int jj = 0; jj < cnt; ++jj)
                acc = fmaf(la[jj], h[(size_t)ls[jj] * F + tid], acc);
        }
    }
    if (tid < F) outh[(size_t)n * F + tid] = fmaxf(acc + bias[tid], 0.f);
}

/* ---------- LSTM recurrence: 2 blocks (fwd/bwd), 512 threads ---------- */
__global__ __launch_bounds__(512) void lstm_dir(const float* __restrict__ xpF, const float* __restrict__ xpB,
                                                const float* __restrict__ WhhF, const float* __restrict__ WhhB,
                                                float* __restrict__ y, int T) {
    const int dir = blockIdx.x;
    const float* xp = dir ? xpB : xpF;
    const float* Whh = dir ? WhhB : WhhF;
    const int g = threadIdx.x;
    float w[128];
#pragma unroll
    for (int k = 0; k < 128; ++k) w[k] = Whh[g * 128 + k];
    __shared__ __align__(16) float h_lds[128];
    __shared__ float gbuf[512];
    if (g < 128) h_lds[g] = 0.f;
    float c = 0.f;
    float xv = xp[(size_t)(dir ? (T - 1) : 0) * 512 + g];
    float xv1 = xp[(size_t)(dir ? (T - 2) : 1) * 512 + g];
    __syncthreads();
    for (int s = 0; s < T; ++s) {
        const int t = dir ? (T - 1 - s) : s;
        float xv2 = 0.f;
        if (s + 2 < T) {
            int t2 = dir ? (T - 3 - s) : (s + 2);
            xv2 = xp[(size_t)t2 * 512 + g];
        }
        float acc = xv;
#pragma unroll
        for (int k = 0; k < 128; k += 4) {
            float4 hv = *(const float4*)(h_lds + k);
            acc = fmaf(w[k + 0], hv.x, acc);
            acc = fmaf(w[k + 1], hv.y, acc);
            acc = fmaf(w[k + 2], hv.z, acc);
            acc = fmaf(w[k + 3], hv.w, acc);
        }
        gbuf[g] = acc;
        __syncthreads();
        if (g < 128) {
            float gi = gbuf[g], gf = gbuf[128 + g], gg = gbuf[256 + g], go = gbuf[384 + g];
            float i_ = 1.f / (1.f + __expf(-gi));
            float f_ = 1.f / (1.f + __expf(-gf));
            float o_ = 1.f / (1.f + __expf(-go));
            c = f_ * c + i_ * tanh_fast(gg);
            float hh = o_ * tanh_fast(c);
            h_lds[g] = hh;
            y[(size_t)t * 256 + dir * 128 + g] = hh;
        }
        __syncthreads();
        xv = xv1; xv1 = xv2;
    }
}

__global__ __launch_bounds__(256) void k_pool(const float* __restrict__ y, float* __restrict__ pooled) {
    const int b = blockIdx.x, f = threadIdx.x;
    float s = 0.f;
#pragma unroll
    for (int g = 0; g < 16; ++g) s += y[((size_t)b * 16 + g) * 256 + f];
    pooled[b * 256 + f] = s * (1.f / 16.f);
}

extern "C" void kernel_launch(void* const* d_in, const int* in_sizes, int n_in,
                              void* d_out, int out_size, void* d_ws, size_t ws_size,
                              hipStream_t stream) {
    const float* x    = (const float*)d_in[0];
    const int*   ei   = (const int*)d_in[1];
    const float* W1   = (const float*)d_in[2];
    const float* a1s  = (const float*)d_in[3];
    const float* a1d  = (const float*)d_in[4];
    const float* b1   = (const float*)d_in[5];
    const float* W2   = (const float*)d_in[6];
    const float* a2s  = (const float*)d_in[7];
    const float* a2d  = (const float*)d_in[8];
    const float* b2   = (const float*)d_in[9];
    const float* W3   = (const float*)d_in[10];
    const float* a3s  = (const float*)d_in[11];
    const float* a3d  = (const float*)d_in[12];
    const float* b3   = (const float*)d_in[13];
    const float* Wih0 = (const float*)d_in[14];
    const float* Whh0 = (const float*)d_in[15];
    const float* bih0 = (const float*)d_in[16];
    const float* bhh0 = (const float*)d_in[17];
    const float* Wih0r= (const float*)d_in[18];
    const float* Whh0r= (const float*)d_in[19];
    const float* bih0r= (const float*)d_in[20];
    const float* bhh0r= (const float*)d_in[21];
    const float* Wih1 = (const float*)d_in[22];
    const float* Whh1 = (const float*)d_in[23];
    const float* bih1 = (const float*)d_in[24];
    const float* bhh1 = (const float*)d_in[25];
    const float* Wih1r= (const float*)d_in[26];
    const float* Whh1r= (const float*)d_in[27];
    const float* bih1r= (const float*)d_in[28];
    const float* bhh1r= (const float*)d_in[29];
    const float* fc1w = (const float*)d_in[30];
    const float* fc1b = (const float*)d_in[31];
    const float* g1   = (const float*)d_in[32];
    const float* be1  = (const float*)d_in[33];
    const float* fc2w = (const float*)d_in[34];
    const float* fc2b = (const float*)d_in[35];
    const float* g2   = (const float*)d_in[36];
    const float* be2  = (const float*)d_in[37];
    const float* fc3w = (const float*)d_in[38];
    const float* fc3b = (const float*)d_in[39];
    float* out = (float*)d_out;

    char* p = (char*)d_ws;
    auto alloc = [&](size_t bytes) -> void* {
        void* r = (void*)p;
        p += (bytes + 255) & ~(size_t)255;
        return r;
    };
    int* src_i   = (int*)alloc((size_t)ET * 4);
    int* dst_i   = (int*)alloc((size_t)ET * 4);
    int* counts  = (int*)alloc((size_t)N_NODES * 4);
    int* rowptr  = (int*)alloc((size_t)(N_NODES + 1) * 4);
    int* cursor  = (int*)alloc((size_t)N_NODES * 4);
    int* esort   = (int*)alloc((size_t)ET * 4);
    float* hbuf  = (float*)alloc((size_t)N_NODES * 256 * 4);
    float* bufA  = (float*)alloc((size_t)N_NODES * 256 * 4);
    float* bufB  = (float*)alloc((size_t)N_NODES * 256 * 4);
    float* ssrc  = (float*)alloc((size_t)N_NODES * 4);
    float* sdst  = (float*)alloc((size_t)N_NODES * 4);
    float* xpF   = (float*)alloc((size_t)N_NODES * 512 * 4);
    float* xpB   = (float*)alloc((size_t)N_NODES * 512 * 4);
    float* pooled= (float*)alloc((size_t)512 * 256 * 4);
    float* z1    = (float*)alloc((size_t)512 * 256 * 4);
    float* z2    = (float*)alloc((size_t)512 * 64 * 4);

    const int EB = (ET + 255) / 256;
    hipMemsetAsync(counts, 0, (size_t)N_NODES * 4, stream);
    k_edges<<<EB, 256, 0, stream>>>(ei, src_i, dst_i, out + O_SD, counts);
    k_scan<<<1, 1024, 0, stream>>>(counts, rowptr, cursor);
    k_scatter<<<EB, 256, 0, stream>>>(dst_i, cursor, esort);

    /* GAT layer 1: x[8192,1024] @ W1[1024,128] */
    gemm_nn<<<dim3(128, 2), 256, 0, stream>>>(x, W1, hbuf, N_NODES, 128, 1024);
    attn_scores<<<N_NODES / 4, 256, 0, stream>>>(hbuf, a1s, a1d, ssrc, sdst, 128);
    gat_agg<<<N_NODES, 256, 0, stream>>>(hbuf, ssrc, sdst, rowptr, esort, src_i, b1, bufA, out + O_A1, 128);

    /* GAT layer 2: bufA[8192,128] @ W2[128,256] */
    gemm_nn<<<dim3(128, 4), 256, 0, stream>>>(bufA, W2, hbuf, N_NODES, 256, 128);
    attn_scores<<<N_NODES / 4, 256, 0, stream>>>(hbuf, a2s, a2d, ssrc, sdst, 256);
    gat_agg<<<N_NODES, 256, 0, stream>>>(hbuf, ssrc, sdst, rowptr, esort, src_i, b2, bufB, out + O_A2, 256);

    /* GAT layer 3: bufB[8192,256] @ W3[256,128] */
    gemm_nn<<<dim3(128, 2), 256, 0, stream>>>(bufB, W3, hbuf, N_NODES, 128, 256);
    attn_scores<<<N_NODES / 4, 256, 0, stream>>>(hbuf, a3s, a3d, ssrc, sdst, 128);
    gat_agg<<<N_NODES, 256, 0, stream>>>(hbuf, ssrc, sdst, rowptr, esort, src_i, b3, bufA, out + O_A3, 128);

    /* LSTM layer 0: input bufA[8192,128] -> y0 = bufB[8192,256] */
    gemm_tn<<<dim3(128, 8), 256, 0, stream>>>(bufA, Wih0,  xpF, N_NODES, 512, 128, bih0,  bhh0,  0, nullptr, nullptr);
    gemm_tn<<<dim3(128, 8), 256, 0, stream>>>(bufA, Wih0r, xpB, N_NODES, 512, 128, bih0r, bhh0r, 0, nullptr, nullptr);
    lstm_dir<<<2, 512, 0, stream>>>(xpF, xpB, Whh0, Whh0r, bufB, N_NODES);

    /* LSTM layer 1: input bufB[8192,256] -> y1 = hbuf[8192,256] */
    gemm_tn<<<dim3(128, 8), 256, 0, stream>>>(bufB, Wih1,  xpF, N_NODES, 512, 256, bih1,  bhh1,  0, nullptr, nullptr);
    gemm_tn<<<dim3(128, 8), 256, 0, stream>>>(bufB, Wih1r, xpB, N_NODES, 512, 256, bih1r, bhh1r, 0, nullptr, nullptr);
    lstm_dir<<<2, 512, 0, stream>>>(xpF, xpB, Whh1, Whh1r, hbuf, N_NODES);

    /* pool + head */
    k_pool<<<512, 256, 0, stream>>>(hbuf, pooled);
    gemm_tn<<<dim3(8, 4), 256, 0, stream>>>(pooled, fc1w, z1, 512, 256, 256, fc1b, nullptr, 1, g1, be1);
    gemm_tn<<<dim3(8, 1), 256, 0, stream>>>(z1, fc2w, z2, 512, 64, 256, fc2b, nullptr, 1, g2, be2);
    gemm_tn<<<dim3(8, 1), 256, 0, stream>>>(z2, fc3w, out, 512, 3, 64, fc3b, nullptr, 0, nullptr, nullptr);
}

// Round 2
// 11791.864 us; speedup vs baseline: 1.4299x; 1.4299x over previous
//
#include <hip/hip_runtime.h>

#define N_NODES 8192
#define E_EDGES 262144
#define ET (E_EDGES + N_NODES)   /* 270336 edges incl. self-loops */

/* d_out layout (float32):
   [0,1536) logits; a1 @1536; a2 @271872; a3 @542208; srcdst @812544 (2 x ET) */
#define O_A1 1536
#define O_A2 (O_A1 + ET)
#define O_A3 (O_A2 + ET)
#define O_SD (O_A3 + ET)

typedef _Float16 half8 __attribute__((ext_vector_type(8)));
typedef float f32x4 __attribute__((ext_vector_type(4)));

static __device__ __forceinline__ float tanh_fast(float x) {
    x = fminf(fmaxf(x, -15.f), 15.f);
    float e = __expf(2.f * x);
    return (e - 1.f) / (e + 1.f);
}

/* ---------- edge prep ---------- */
__global__ __launch_bounds__(256) void k_edges(const int* __restrict__ ei,
                                               int* __restrict__ src_i, int* __restrict__ dst_i,
                                               float* __restrict__ out_sd, int* __restrict__ counts) {
    int i = blockIdx.x * 256 + threadIdx.x;
    if (i >= ET) return;
    int s, d;
    if (i < E_EDGES) { s = ei[i]; d = ei[E_EDGES + i]; }
    else { s = d = i - E_EDGES; }
    src_i[i] = s; dst_i[i] = d;
    out_sd[i] = (float)s;
    out_sd[ET + i] = (float)d;
    atomicAdd(&counts[d], 1);
}

__global__ __launch_bounds__(1024) void k_scan(const int* __restrict__ counts,
                                               int* __restrict__ rowptr, int* __restrict__ cursor) {
    __shared__ int part[1024];
    const int tid = threadIdx.x;
    const int base = tid * 8;
    int loc[8]; int run = 0;
#pragma unroll
    for (int i = 0; i < 8; ++i) { loc[i] = run; run += counts[base + i]; }
    part[tid] = run;
    __syncthreads();
    for (int off = 1; off < 1024; off <<= 1) {
        int v = (tid >= off) ? part[tid - off] : 0;
        __syncthreads();
        part[tid] += v;
        __syncthreads();
    }
    int pre = tid ? part[tid - 1] : 0;
#pragma unroll
    for (int i = 0; i < 8; ++i) {
        int v = pre + loc[i];
        rowptr[base + i] = v;
        cursor[base + i] = v;
    }
    if (tid == 1023) rowptr[N_NODES] = part[1023];
}

__global__ __launch_bounds__(256) void k_scatter(const int* __restrict__ dst_i,
                                                 int* __restrict__ cursor, int* __restrict__ esort) {
    int i = blockIdx.x * 256 + threadIdx.x;
    if (i >= ET) return;
    int pos = atomicAdd(&cursor[dst_i[i]], 1);
    esort[pos] = i;
}

/* ---------- GEMM: C[M,N] = A[M,K] * B[K,N]  (B row-major k-major) ---------- */
__global__ __launch_bounds__(256) void gemm_nn(const float* __restrict__ A, const float* __restrict__ B,
                                               float* __restrict__ C, int M, int N, int K) {
    __shared__ __align__(16) float As[16][68];
    __shared__ __align__(16) float Bs[16][68];
    const int tid = threadIdx.x;
    const int tx = tid & 15, ty = tid >> 4;
    const int m0 = blockIdx.x * 64, n0 = blockIdx.y * 64;
    float acc[4][4] = {};
    for (int k0 = 0; k0 < K; k0 += 16) {
        const int ar = tid >> 4, ac = tid & 15;
#pragma unroll
        for (int i = 0; i < 4; ++i)
            As[ac][ar + i * 16] = A[(size_t)(m0 + ar + i * 16) * K + k0 + ac];
        const int br = tid >> 6, bc = tid & 63;
#pragma unroll
        for (int i = 0; i < 4; ++i)
            Bs[br + i * 4][bc] = B[(size_t)(k0 + br + i * 4) * N + n0 + bc];
        __syncthreads();
#pragma unroll
        for (int kk = 0; kk < 16; ++kk) {
            float4 a4 = *(const float4*)&As[kk][ty * 4];
            float4 b4 = *(const float4*)&Bs[kk][tx * 4];
            float av[4] = {a4.x, a4.y, a4.z, a4.w};
            float bv[4] = {b4.x, b4.y, b4.z, b4.w};
#pragma unroll
            for (int i = 0; i < 4; ++i)
#pragma unroll
                for (int j = 0; j < 4; ++j) acc[i][j] = fmaf(av[i], bv[j], acc[i][j]);
        }
        __syncthreads();
    }
#pragma unroll
    for (int i = 0; i < 4; ++i)
#pragma unroll
        for (int j = 0; j < 4; ++j)
            C[(size_t)(m0 + ty * 4 + i) * N + n0 + tx * 4 + j] = acc[i][j];
}

/* ---------- GEMM: C[M,N] = A[M,K] * B[N,K]^T, fused epilogue ---------- */
__global__ __launch_bounds__(256) void gemm_tn(const float* __restrict__ A, const float* __restrict__ B,
                                               float* __restrict__ C, int M, int N, int K,
                                               const float* __restrict__ b1, const float* __restrict__ b2,
                                               int do_relu, const float* __restrict__ bng,
                                               const float* __restrict__ bnb) {
    __shared__ __align__(16) float As[16][68];
    __shared__ __align__(16) float Bs[16][68];
    const int tid = threadIdx.x;
    const int tx = tid & 15, ty = tid >> 4;
    const int m0 = blockIdx.x * 64, n0 = blockIdx.y * 64;
    float acc[4][4] = {};
    for (int k0 = 0; k0 < K; k0 += 16) {
        const int ar = tid >> 4, ac = tid & 15;
#pragma unroll
        for (int i = 0; i < 4; ++i)
            As[ac][ar + i * 16] = A[(size_t)(m0 + ar + i * 16) * K + k0 + ac];
#pragma unroll
        for (int i = 0; i < 4; ++i) {
            int n = n0 + (tid >> 4) + i * 16;
            Bs[tid & 15][(tid >> 4) + i * 16] = (n < N) ? B[(size_t)n * K + k0 + (tid & 15)] : 0.f;
        }
        __syncthreads();
#pragma unroll
        for (int kk = 0; kk < 16; ++kk) {
            float4 a4 = *(const float4*)&As[kk][ty * 4];
            float4 b4 = *(const float4*)&Bs[kk][tx * 4];
            float av[4] = {a4.x, a4.y, a4.z, a4.w};
            float bv[4] = {b4.x, b4.y, b4.z, b4.w};
#pragma unroll
            for (int i = 0; i < 4; ++i)
#pragma unroll
                for (int j = 0; j < 4; ++j) acc[i][j] = fmaf(av[i], bv[j], acc[i][j]);
        }
        __syncthreads();
    }
#pragma unroll
    for (int i = 0; i < 4; ++i)
#pragma unroll
        for (int j = 0; j < 4; ++j) {
            int n = n0 + tx * 4 + j;
            if (n >= N) continue;
            float v = acc[i][j];
            if (b1) v += b1[n];
            if (b2) v += b2[n];
            if (do_relu) v = fmaxf(v, 0.f);
            if (bng) v = v * (bng[n] * rsqrtf(1.f + 1e-5f)) + bnb[n];
            C[(size_t)(m0 + ty * 4 + i) * N + n] = v;
        }
}

/* ---------- per-node attention scores ---------- */
__global__ __launch_bounds__(256) void attn_scores(const float* __restrict__ h,
                                                   const float* __restrict__ a_s, const float* __restrict__ a_d,
                                                   float* __restrict__ ssrc, float* __restrict__ sdst, int F) {
    const int wave = threadIdx.x >> 6, lane = threadIdx.x & 63;
    const int n = blockIdx.x * 4 + wave;
    const float* hr = h + (size_t)n * F;
    float va = 0.f, vd = 0.f;
    for (int f = lane; f < F; f += 64) { float hv = hr[f]; va += hv * a_s[f]; vd += hv * a_d[f]; }
    for (int o = 32; o; o >>= 1) { va += __shfl_down(va, o); vd += __shfl_down(vd, o); }
    if (lane == 0) { ssrc[n] = va; sdst[n] = vd; }
}

/* ---------- softmax + aggregate per dst node ---------- */
__global__ __launch_bounds__(256) void gat_agg(const float* __restrict__ h,
                                               const float* __restrict__ ssrc, const float* __restrict__ sdst,
                                               const int* __restrict__ rowptr, const int* __restrict__ esort,
                                               const int* __restrict__ src_i, const float* __restrict__ bias,
                                               float* __restrict__ outh, float* __restrict__ alpha_out, int F) {
    const int n = blockIdx.x, tid = threadIdx.x;
    const int r0 = rowptr[n], r1 = rowptr[n + 1];
    const int deg = r1 - r0;
    const float sd = sdst[n];
    __shared__ float redA[4], redB[4];
    float m = -1e30f;
    for (int j = tid; j < deg; j += 256) {
        int eid = esort[r0 + j];
        float e = ssrc[src_i[eid]] + sd;
        e = (e >= 0.f) ? e : 0.2f * e;
        m = fmaxf(m, e);
    }
    for (int o = 32; o; o >>= 1) m = fmaxf(m, __shfl_down(m, o));
    if ((tid & 63) == 0) redA[tid >> 6] = m;
    __syncthreads();
    m = fmaxf(fmaxf(redA[0], redA[1]), fmaxf(redA[2], redA[3]));
    float s = 0.f;
    for (int j = tid; j < deg; j += 256) {
        int eid = esort[r0 + j];
        float e = ssrc[src_i[eid]] + sd;
        e = (e >= 0.f) ? e : 0.2f * e;
        s += __expf(e - m);
    }
    for (int o = 32; o; o >>= 1) s += __shfl_down(s, o);
    if ((tid & 63) == 0) redB[tid >> 6] = s;
    __syncthreads();
    s = redB[0] + redB[1] + redB[2] + redB[3];
    const float inv = 1.f / (s + 1e-16f);
    __shared__ float la[256];
    __shared__ int ls[256];
    float acc = 0.f;
    for (int base = 0; base < deg; base += 256) {
        __syncthreads();
        int j = base + tid;
        if (j < deg) {
            int eid = esort[r0 + j];
            int sidx = src_i[eid];
            float e = ssrc[sidx] + sd;
            e = (e >= 0.f) ? e : 0.2f * e;
            float al = __expf(e - m) * inv;
            la[tid] = al; ls[tid] = sidx;
            alpha_out[eid] = al;
        }
        __syncthreads();
        int cnt = min(256, deg - base);
        if (tid < F) {
            for (int jj = 0; jj < cnt; ++jj)
                acc = fmaf(la[jj], h[(size_t)ls[jj] * F + tid], acc);
        }
    }
    if (tid < F) outh[(size_t)n * F + tid] = fmaxf(acc + bias[tid], 0.f);
}

/* ---------- LSTM recurrence via MFMA: 2 blocks (fwd/bwd), 512 threads ----------
 * Whh resident in VGPRs as A-fragments (f16). h broadcast as B-operand from a
 * 256 B f16 LDS buffer (4 ds_read_b128/wave/step instead of 32). xp[t] rides in
 * as the MFMA C operand, prefetched 1 step ahead. Gates hit LDS once (f32),
 * cell update on threads 0-127, c in registers, h stored back as f16. */
__global__ __launch_bounds__(512) void lstm_mfma(const float* __restrict__ xpF, const float* __restrict__ xpB,
                                                 const float* __restrict__ WhhF, const float* __restrict__ WhhB,
                                                 float* __restrict__ y, int T) {
    const int dir = blockIdx.x;
    const float* __restrict__ xp  = dir ? xpB : xpF;
    const float* __restrict__ Whh = dir ? WhhB : WhhF;
    const int tid  = threadIdx.x;
    const int w    = tid >> 6;
    const int lane = tid & 63;
    const int col  = lane & 15;       /* A: m index; D: n index */
    const int quad = lane >> 4;       /* A/B: k = quad*8+j; D: row = quad*4+reg */
    const int g0   = w * 64;

    /* resident Whh A-fragments: wfrag[mt][ks] = Whh[g0+mt*16+col][ks*32+quad*8 .. +7] */
    half8 wfrag[4][4];
#pragma unroll
    for (int mt = 0; mt < 4; ++mt) {
        const float* wr = Whh + (size_t)(g0 + mt * 16 + col) * 128;
#pragma unroll
        for (int ks = 0; ks < 4; ++ks) {
            const float* src = wr + ks * 32 + quad * 8;
            half8 f;
#pragma unroll
            for (int j = 0; j < 8; ++j) f[j] = (_Float16)src[j];
            wfrag[mt][ks] = f;
        }
    }

    __shared__ __align__(16) _Float16 h_lds[128];
    __shared__ __align__(16) float gbuf[512];
    float c = 0.f;
    if (tid < 128) h_lds[tid] = (_Float16)0.f;

    /* prefetch xp for step 0 */
    f32x4 tmp[4];
    {
        const int t0 = dir ? (T - 1) : 0;
        const float* b = xp + (size_t)t0 * 512 + g0 + quad * 4;
#pragma unroll
        for (int mt = 0; mt < 4; ++mt) tmp[mt] = *(const f32x4*)(b + mt * 16);
    }
    __syncthreads();

    for (int s = 0; s < T; ++s) {
        const int t = dir ? (T - 1 - s) : s;
        /* B-fragments: h replicated across n */
        half8 hb[4];
#pragma unroll
        for (int ks = 0; ks < 4; ++ks)
            hb[ks] = *(const half8*)(h_lds + ks * 32 + quad * 8);
        f32x4 acc[4];
#pragma unroll
        for (int mt = 0; mt < 4; ++mt) {
            f32x4 a = tmp[mt];
#pragma unroll
            for (int ks = 0; ks < 4; ++ks)
                a = __builtin_amdgcn_mfma_f32_16x16x32_f16(wfrag[mt][ks], hb[ks], a, 0, 0, 0);
            acc[mt] = a;
        }
        /* prefetch next step's xp (hides global latency across the barrier) */
        if (s + 1 < T) {
            const int tn = dir ? (T - 2 - s) : (s + 1);
            const float* b = xp + (size_t)tn * 512 + g0 + quad * 4;
#pragma unroll
            for (int mt = 0; mt < 4; ++mt) tmp[mt] = *(const f32x4*)(b + mt * 16);
        }
        /* gates -> LDS (col 0 lanes hold the canonical copy) */
        if (col == 0) {
#pragma unroll
            for (int mt = 0; mt < 4; ++mt)
                *(f32x4*)(gbuf + g0 + mt * 16 + quad * 4) = acc[mt];
        }
        __syncthreads();
        if (tid < 128) {
            float gi = gbuf[tid], gf = gbuf[128 + tid], gg = gbuf[256 + tid], go = gbuf[384 + tid];
            float i_ = 1.f / (1.f + __expf(-gi));
            float f_ = 1.f / (1.f + __expf(-gf));
            float o_ = 1.f / (1.f + __expf(-go));
            c = f_ * c + i_ * tanh_fast(gg);
            float hh = o_ * tanh_fast(c);
            h_lds[tid] = (_Float16)hh;
            y[(size_t)t * 256 + dir * 128 + tid] = hh;
        }
        __syncthreads();
    }
}

__global__ __launch_bounds__(256) void k_pool(const float* __restrict__ y, float* __restrict__ pooled) {
    const int b = blockIdx.x, f = threadIdx.x;
    float s = 0.f;
#pragma unroll
    for (int g = 0; g < 16; ++g) s += y[((size_t)b * 16 + g) * 256 + f];
    pooled[b * 256 + f] = s * (1.f / 16.f);
}

extern "C" void kernel_launch(void* const* d_in, const int* in_sizes, int n_in,
                              void* d_out, int out_size, void* d_ws, size_t ws_size,
                              hipStream_t stream) {
    const float* x    = (const float*)d_in[0];
    const int*   ei   = (const int*)d_in[1];
    const float* W1   = (const float*)d_in[2];
    const float* a1s  = (const float*)d_in[3];
    const float* a1d  = (const float*)d_in[4];
    const float* b1   = (const float*)d_in[5];
    const float* W2   = (const float*)d_in[6];
    const float* a2s  = (const float*)d_in[7];
    const float* a2d  = (const float*)d_in[8];
    const float* b2   = (const float*)d_in[9];
    const float* W3   = (const float*)d_in[10];
    const float* a3s  = (const float*)d_in[11];
    const float* a3d  = (const float*)d_in[12];
    const float* b3   = (const float*)d_in[13];
    const float* Wih0 = (const float*)d_in[14];
    const float* Whh0 = (const float*)d_in[15];
    const float* bih0 = (const float*)d_in[16];
    const float* bhh0 = (const float*)d_in[17];
    const float* Wih0r= (const float*)d_in[18];
    const float* Whh0r= (const float*)d_in[19];
    const float* bih0r= (const float*)d_in[20];
    const float* bhh0r= (const float*)d_in[21];
    const float* Wih1 = (const float*)d_in[22];
    const float* Whh1 = (const float*)d_in[23];
    const float* bih1 = (const float*)d_in[24];
    const float* bhh1 = (const float*)d_in[25];
    const float* Wih1r= (const float*)d_in[26];
    const float* Whh1r= (const float*)d_in[27];
    const float* bih1r= (const float*)d_in[28];
    const float* bhh1r= (const float*)d_in[29];
    const float* fc1w = (const float*)d_in[30];
    const float* fc1b = (const float*)d_in[31];
    const float* g1   = (const float*)d_in[32];
    const float* be1  = (const float*)d_in[33];
    const float* fc2w = (const float*)d_in[34];
    const float* fc2b = (const float*)d_in[35];
    const float* g2   = (const float*)d_in[36];
    const float* be2  = (const float*)d_in[37];
    const float* fc3w = (const float*)d_in[38];
    const float* fc3b = (const float*)d_in[39];
    float* out = (float*)d_out;

    char* p = (char*)d_ws;
    auto alloc = [&](size_t bytes) -> void* {
        void* r = (void*)p;
        p += (bytes + 255) & ~(size_t)255;
        return r;
    };
    int* src_i   = (int*)alloc((size_t)ET * 4);
    int* dst_i   = (int*)alloc((size_t)ET * 4);
    int* counts  = (int*)alloc((size_t)N_NODES * 4);
    int* rowptr  = (int*)alloc((size_t)(N_NODES + 1) * 4);
    int* cursor  = (int*)alloc((size_t)N_NODES * 4);
    int* esort   = (int*)alloc((size_t)ET * 4);
    float* hbuf  = (float*)alloc((size_t)N_NODES * 256 * 4);
    float* bufA  = (float*)alloc((size_t)N_NODES * 256 * 4);
    float* bufB  = (float*)alloc((size_t)N_NODES * 256 * 4);
    float* ssrc  = (float*)alloc((size_t)N_NODES * 4);
    float* sdst  = (float*)alloc((size_t)N_NODES * 4);
    float* xpF   = (float*)alloc((size_t)N_NODES * 512 * 4);
    float* xpB   = (float*)alloc((size_t)N_NODES * 512 * 4);
    float* pooled= (float*)alloc((size_t)512 * 256 * 4);
    float* z1    = (float*)alloc((size_t)512 * 256 * 4);
    float* z2    = (float*)alloc((size_t)512 * 64 * 4);

    const int EB = (ET + 255) / 256;
    hipMemsetAsync(counts, 0, (size_t)N_NODES * 4, stream);
    k_edges<<<EB, 256, 0, stream>>>(ei, src_i, dst_i, out + O_SD, counts);
    k_scan<<<1, 1024, 0, stream>>>(counts, rowptr, cursor);
    k_scatter<<<EB, 256, 0, stream>>>(dst_i, cursor, esort);

    /* GAT layer 1: x[8192,1024] @ W1[1024,128] */
    gemm_nn<<<dim3(128, 2), 256, 0, stream>>>(x, W1, hbuf, N_NODES, 128, 1024);
    attn_scores<<<N_NODES / 4, 256, 0, stream>>>(hbuf, a1s, a1d, ssrc, sdst, 128);
    gat_agg<<<N_NODES, 256, 0, stream>>>(hbuf, ssrc, sdst, rowptr, esort, src_i, b1, bufA, out + O_A1, 128);

    /* GAT layer 2: bufA[8192,128] @ W2[128,256] */
    gemm_nn<<<dim3(128, 4), 256, 0, stream>>>(bufA, W2, hbuf, N_NODES, 256, 128);
    attn_scores<<<N_NODES / 4, 256, 0, stream>>>(hbuf, a2s, a2d, ssrc, sdst, 256);
    gat_agg<<<N_NODES, 256, 0, stream>>>(hbuf, ssrc, sdst, rowptr, esort, src_i, b2, bufB, out + O_A2, 256);

    /* GAT layer 3: bufB[8192,256] @ W3[256,128] */
    gemm_nn<<<dim3(128, 2), 256, 0, stream>>>(bufB, W3, hbuf, N_NODES, 128, 256);
    attn_scores<<<N_NODES / 4, 256, 0, stream>>>(hbuf, a3s, a3d, ssrc, sdst, 128);
    gat_agg<<<N_NODES, 256, 0, stream>>>(hbuf, ssrc, sdst, rowptr, esort, src_i, b3, bufA, out + O_A3, 128);

    /* LSTM layer 0: input bufA[8192,128] -> y0 = bufB[8192,256] */
    gemm_tn<<<dim3(128, 8), 256, 0, stream>>>(bufA, Wih0,  xpF, N_NODES, 512, 128, bih0,  bhh0,  0, nullptr, nullptr);
    gemm_tn<<<dim3(128, 8), 256, 0, stream>>>(bufA, Wih0r, xpB, N_NODES, 512, 128, bih0r, bhh0r, 0, nullptr, nullptr);
    lstm_mfma<<<2, 512, 0, stream>>>(xpF, xpB, Whh0, Whh0r, bufB, N_NODES);

    /* LSTM layer 1: input bufB[8192,256] -> y1 = hbuf[8192,256] */
    gemm_tn<<<dim3(128, 8), 256, 0, stream>>>(bufB, Wih1,  xpF, N_NODES, 512, 256, bih1,  bhh1,  0, nullptr, nullptr);
    gemm_tn<<<dim3(128, 8), 256, 0, stream>>>(bufB, Wih1r, xpB, N_NODES, 512, 256, bih1r, bhh1r, 0, nullptr, nullptr);
    lstm_mfma<<<2, 512, 0, stream>>>(xpF, xpB, Whh1, Whh1r, hbuf, N_NODES);

    /* pool + head */
    k_pool<<<512, 256, 0, stream>>>(hbuf, pooled);
    gemm_tn<<<dim3(8, 4), 256, 0, stream>>>(pooled, fc1w, z1, 512, 256, 256, fc1b, nullptr, 1, g1, be1);
    gemm_tn<<<dim3(8, 1), 256, 0, stream>>>(z1, fc2w, z2, 512, 64, 256, fc2b, nullptr, 1, g2, be2);
    gemm_tn<<<dim3(8, 1), 256, 0, stream>>>(z2, fc3w, out, 512, 3, 64, fc3b, nullptr, 0, nullptr, nullptr);
}